// Round 1
// baseline (519.337 us; speedup 1.0000x reference)
//
#include <hip/hip_runtime.h>
#include <math.h>

// Fused CNN classifier: conv(1->8,3x3,s2,p1)+ReLU -> conv(8->16,3x3,s2,p1)+ReLU
//                       -> FC(784->1) -> softplus+0.001 -> 1-exp(-r) -> clip
// B=65536 images of 1x28x28 fp32.
//
// Structure: block=256 (4 waves), one wave per image. Image staged to LDS
// (zero-padded 30 rows x stride-31). Lane = conv2 spatial position (49 of 64
// active). Each lane: 7x7 input window in regs (read LDS once), recompute its
// 3x3 z1 window per c1 (conv1 recompute 2.25x, cheap), accumulate 16 c2 chans
// in regs, fold FC weight immediately -> no z1/z2 LDS traffic. Conv weights
// are wave-uniform -> s_load + SGPR-operand v_fma (no VMEM/LDS for weights).

#define IMG_PER_BLOCK 4
#define P_ROWS 30
#define P_STRIDE 31               // row stride 31: breaks stride-4 bank pattern
#define P_FLOATS (P_ROWS * P_STRIDE)   // 930 floats per image

__global__ __launch_bounds__(256, 4) void fused_cnn_kernel(
    const float* __restrict__ x,
    const float* __restrict__ W1, const float* __restrict__ b1,
    const float* __restrict__ W2, const float* __restrict__ b2,
    const float* __restrict__ Wfc, const float* __restrict__ bfc,
    float* __restrict__ out, int nimg)
{
    __shared__ float P[IMG_PER_BLOCK * P_FLOATS];

    const int tid  = threadIdx.x;
    const int img0 = blockIdx.x * IMG_PER_BLOCK;

    // Zero LDS (covers padding borders).
    for (int i = tid; i < IMG_PER_BLOCK * P_FLOATS; i += 256) P[i] = 0.f;
    __syncthreads();

    // Stage 4 images = 3136 contiguous floats, coalesced float4 loads.
    // 28 % 4 == 0 so a float4 never crosses an image row.
    {
        const float4* src = (const float4*)(x + (size_t)img0 * 784);
        const int nvec = IMG_PER_BLOCK * 196;                 // 784 float4s
        for (int f = tid; f < nvec; f += 256) {
            int flat = f * 4;
            int im   = flat / 784;
            if (img0 + im < nimg) {
                float4 v = src[f];
                int rem = flat - im * 784;
                int yy  = rem / 28;
                int xx  = rem - yy * 28;
                float* dst = &P[im * P_FLOATS + (yy + 1) * P_STRIDE + (xx + 1)];
                dst[0] = v.x; dst[1] = v.y; dst[2] = v.z; dst[3] = v.w;
            }
        }
    }
    __syncthreads();

    const int wave = tid >> 6;
    const int lane = tid & 63;
    const int img  = img0 + wave;
    const float* __restrict__ Pimg = &P[wave * P_FLOATS];

    float fc = 0.f;

    if (lane < 49) {
        const int oy = lane / 7;        // conv2 output row  0..6
        const int ox = lane - oy * 7;   // conv2 output col  0..6

        // 7x7 input window (padded coords), rows/cols 4o-2 .. 4o+4.
        // Negative indices clamp to 0: those values only feed z1 positions
        // that are masked to zero below, so garbage there is harmless.
        float win[7][7];
        {
            const int rbase = 4 * oy - 2;
            const int cbase = 4 * ox - 2;
            #pragma unroll
            for (int r = 0; r < 7; r++) {
                int rr = rbase + r; rr = rr < 0 ? 0 : rr;
                const float* rowp = Pimg + rr * P_STRIDE;
                #pragma unroll
                for (int c = 0; c < 7; c++) {
                    int cc = cbase + c; cc = cc < 0 ? 0 : cc;
                    win[r][c] = rowp[cc];
                }
            }
        }

        float acc[16];
        #pragma unroll
        for (int i = 0; i < 16; i++) acc[i] = 0.f;

        for (int c1 = 0; c1 < 8; c1++) {   // uniform loop -> scalar weights
            const float bb = b1[c1];
            float w1r[9];
            #pragma unroll
            for (int k = 0; k < 9; k++) w1r[k] = W1[c1 * 9 + k];

            // z1 window: z1 coords (2oy-1+wy, 2ox-1+wx); window-rel input
            // index = (2wy+ky, 2wx+kx). Mask z1 positions outside the 14x14
            // map (conv2 zero-padding) to 0.
            float z1w[9];
            #pragma unroll
            for (int wy = 0; wy < 3; wy++) {
                #pragma unroll
                for (int wx = 0; wx < 3; wx++) {
                    float v = bb;
                    #pragma unroll
                    for (int ky = 0; ky < 3; ky++)
                        #pragma unroll
                        for (int kx = 0; kx < 3; kx++)
                            v = fmaf(win[2 * wy + ky][2 * wx + kx],
                                     w1r[ky * 3 + kx], v);
                    v = fmaxf(v, 0.f);
                    const bool ok = ((wy > 0) || (oy > 0)) &&
                                    ((wx > 0) || (ox > 0));
                    z1w[wy * 3 + wx] = ok ? v : 0.f;
                }
            }

            // conv2 partial: acc[c2] += z1w . W2[c2][c1][:]
            const float* __restrict__ w2c = W2 + c1 * 9;  // + c2*72 + k
            #pragma unroll
            for (int c2 = 0; c2 < 16; c2++) {
                #pragma unroll
                for (int k = 0; k < 9; k++)
                    acc[c2] = fmaf(z1w[k], w2c[c2 * 72 + k], acc[c2]);
            }
        }

        // bias + ReLU + FC fold (flatten index = c2*49 + oy*7 + ox = c2*49+lane)
        #pragma unroll
        for (int c2 = 0; c2 < 16; c2++) {
            float v = fmaxf(acc[c2] + b2[c2], 0.f);
            fc = fmaf(v, Wfc[c2 * 49 + lane], fc);
        }
    }

    // Wave-wide sum (lanes 49..63 contribute 0).
    #pragma unroll
    for (int off = 32; off > 0; off >>= 1)
        fc += __shfl_down(fc, off, 64);

    if (lane == 0 && img < nimg) {
        float v    = fc + bfc[0];
        float sp   = fmaxf(v, 0.f) + log1pf(expf(-fabsf(v)));  // stable softplus
        float rate = sp + 0.001f;
        float p    = 1.f - expf(-rate);
        p = fminf(fmaxf(p, 1e-6f), 1.f - 1e-6f);
        out[img] = p;
    }
}

extern "C" void kernel_launch(void* const* d_in, const int* in_sizes, int n_in,
                              void* d_out, int out_size, void* d_ws, size_t ws_size,
                              hipStream_t stream) {
    const float* x   = (const float*)d_in[0];
    const float* W1  = (const float*)d_in[1];
    const float* b1  = (const float*)d_in[2];
    const float* W2  = (const float*)d_in[3];
    const float* b2  = (const float*)d_in[4];
    const float* Wfc = (const float*)d_in[5];
    const float* bfc = (const float*)d_in[6];
    float* out = (float*)d_out;

    const int nimg = in_sizes[0] / 784;
    const int grid = (nimg + IMG_PER_BLOCK - 1) / IMG_PER_BLOCK;

    fused_cnn_kernel<<<grid, 256, 0, stream>>>(x, W1, b1, W2, b2, Wfc, bfc,
                                               out, nimg);
}

// Round 2
// 421.375 us; speedup vs baseline: 1.2325x; 1.2325x over previous
//
#include <hip/hip_runtime.h>
#include <math.h>

// Fused CNN classifier: conv(1->8,3x3,s2,p1)+ReLU -> conv(8->16,3x3,s2,p1)+ReLU
//                       -> FC(784->1) -> softplus+0.001 -> 1-exp(-r) -> clip
// B=65536 images of 1x28x28 fp32.
//
// R2: packed-fp32 (v_pk_fma_f32) version. Each wave handles TWO images packed
// as float2 (interleaved per-element in LDS -> one ds_read_b64 per window tap
// fetches both). Window held in VGPRs (barrier after load prevents the
// compiler sinking ds_reads into uses -- the R1 bug: VGPR=44 proved the 49-elem
// window was re-read from LDS per tap). launch_bounds(256,2) -> 256 VGPR cap.

typedef float v2f __attribute__((ext_vector_type(2)));

__device__ __forceinline__ v2f pk_fma(v2f a, float s, v2f c) {
    v2f b = {s, s};
    return __builtin_elementwise_fma(a, b, c);
}
__device__ __forceinline__ v2f pk_relu(v2f a) {
    v2f z = {0.f, 0.f};
    return __builtin_elementwise_max(a, z);
}

#define PAIRS_PER_BLOCK 4          // 4 waves, 1 image-pair per wave
#define P_ROWS 30
#define P_STRIDE 31
#define P_ELEMS (P_ROWS * P_STRIDE)   // 930 float2 per pair

__global__ __launch_bounds__(256, 2) void fused_cnn_kernel(
    const float* __restrict__ x,
    const float* __restrict__ W1, const float* __restrict__ b1,
    const float* __restrict__ W2, const float* __restrict__ b2,
    const float* __restrict__ Wfc, const float* __restrict__ bfc,
    float* __restrict__ out, int nimg)
{
    __shared__ v2f P[PAIRS_PER_BLOCK * P_ELEMS];   // ~29.8 KB

    const int tid  = threadIdx.x;
    const int img0 = blockIdx.x * (PAIRS_PER_BLOCK * 2);

    // Zero LDS (covers the zero-padding border).
    for (int i = tid; i < PAIRS_PER_BLOCK * P_ELEMS; i += 256)
        P[i] = (v2f){0.f, 0.f};
    __syncthreads();

    // Stage 8 images as 4 interleaved pairs. 4 pairs x 196 float4-positions.
    for (int f = tid; f < PAIRS_PER_BLOCK * 196; f += 256) {
        const int pair = f / 196;
        const int pos4 = f - pair * 196;
        const int imgA = img0 + pair * 2;
        float4 a = {0.f, 0.f, 0.f, 0.f}, b = {0.f, 0.f, 0.f, 0.f};
        if (imgA < nimg)
            a = *(const float4*)(x + (size_t)imgA * 784 + pos4 * 4);
        if (imgA + 1 < nimg)
            b = *(const float4*)(x + (size_t)(imgA + 1) * 784 + pos4 * 4);
        const int flat = pos4 * 4;
        const int yy   = flat / 28;
        const int xx   = flat - yy * 28;
        v2f* dst = &P[pair * P_ELEMS + (yy + 1) * P_STRIDE + (xx + 1)];
        dst[0] = (v2f){a.x, b.x};
        dst[1] = (v2f){a.y, b.y};
        dst[2] = (v2f){a.z, b.z};
        dst[3] = (v2f){a.w, b.w};
    }
    __syncthreads();

    const int wave = tid >> 6;
    const int lane = tid & 63;
    const int imgA = img0 + wave * 2;
    const v2f* __restrict__ Pp = &P[wave * P_ELEMS];

    // All 64 lanes run the compute (lanes 49..63 clamp to lane 48's window and
    // are masked out at the FC fold) so the barrier below is divergence-free.
    const int laneC = lane < 49 ? lane : 48;
    const int oy = laneC / 7;          // conv2 output row 0..6
    const int ox = laneC - oy * 7;     // conv2 output col 0..6

    // 7x7 input window (padded coords), rows/cols 4o-2..4o+4. Negative coords
    // clamp to 0: garbage there only feeds z1 positions masked to zero below.
    v2f win[7][7];
    {
        const int rbase = 4 * oy - 2;
        const int cbase = 4 * ox - 2;
        #pragma unroll
        for (int r = 0; r < 7; r++) {
            int rr = rbase + r; rr = rr < 0 ? 0 : rr;
            const v2f* rowp = Pp + rr * P_STRIDE;
            #pragma unroll
            for (int c = 0; c < 7; c++) {
                int cc = cbase + c; cc = cc < 0 ? 0 : cc;
                win[r][c] = rowp[cc];
            }
        }
    }
    // Barrier: forces the 49 ds_read_b64 to complete HERE, pinning win[] in
    // VGPRs (the compiler cannot sink LDS loads past a barrier).
    __syncthreads();

    v2f acc[16];
    #pragma unroll
    for (int i = 0; i < 16; i++) acc[i] = (v2f){0.f, 0.f};

    for (int c1 = 0; c1 < 8; c1++) {       // uniform -> weights in SGPRs
        const float bb = b1[c1];
        float w1r[9];
        #pragma unroll
        for (int k = 0; k < 9; k++) w1r[k] = W1[c1 * 9 + k];

        // z1 element at window pos (wy,wx); input rel index (2wy+ky, 2wx+kx).
        // Mask positions outside the 14x14 z1 map (conv2 zero-padding), then
        // immediately fold into all 16 conv2 accumulators (no z1 array).
        #pragma unroll
        for (int wy = 0; wy < 3; wy++) {
            #pragma unroll
            for (int wx = 0; wx < 3; wx++) {
                v2f v = {bb, bb};
                #pragma unroll
                for (int ky = 0; ky < 3; ky++)
                    #pragma unroll
                    for (int kx = 0; kx < 3; kx++)
                        v = pk_fma(win[2 * wy + ky][2 * wx + kx],
                                   w1r[ky * 3 + kx], v);
                const bool okm = ((wy > 0) || (oy > 0)) &&
                                 ((wx > 0) || (ox > 0));
                const float m = okm ? 1.f : 0.f;
                v = pk_relu(v);
                v2f mm = {m, m};
                v = v * mm;

                const float* __restrict__ w2k = W2 + c1 * 9 + wy * 3 + wx;
                #pragma unroll
                for (int c2 = 0; c2 < 16; c2++)
                    acc[c2] = pk_fma(v, w2k[c2 * 72], acc[c2]);
            }
        }
    }

    // bias + ReLU + FC fold. Flatten index = c2*49 + lane; lanes>=49 get 0.
    v2f fc = {0.f, 0.f};
    #pragma unroll
    for (int c2 = 0; c2 < 16; c2++) {
        v2f z = pk_relu(pk_fma((v2f){1.f, 1.f}, b2[c2], acc[c2]));
        const float wf = (lane < 49) ? Wfc[c2 * 49 + laneC] : 0.f;
        v2f wfv = {wf, wf};
        fc = __builtin_elementwise_fma(z, wfv, fc);
    }

    // Wave-wide sum of both components.
    float fx = fc.x, fy = fc.y;
    #pragma unroll
    for (int off = 32; off > 0; off >>= 1) {
        fx += __shfl_down(fx, off, 64);
        fy += __shfl_down(fy, off, 64);
    }

    if (lane == 0) {
        const float bias = bfc[0];
        #pragma unroll
        for (int s = 0; s < 2; s++) {
            const int img = imgA + s;
            if (img < nimg) {
                float v    = (s == 0 ? fx : fy) + bias;
                float sp   = fmaxf(v, 0.f) + log1pf(expf(-fabsf(v)));
                float rate = sp + 0.001f;
                float p    = 1.f - expf(-rate);
                p = fminf(fmaxf(p, 1e-6f), 1.f - 1e-6f);
                out[img] = p;
            }
        }
    }
}

extern "C" void kernel_launch(void* const* d_in, const int* in_sizes, int n_in,
                              void* d_out, int out_size, void* d_ws, size_t ws_size,
                              hipStream_t stream) {
    const float* x   = (const float*)d_in[0];
    const float* W1  = (const float*)d_in[1];
    const float* b1  = (const float*)d_in[2];
    const float* W2  = (const float*)d_in[3];
    const float* b2  = (const float*)d_in[4];
    const float* Wfc = (const float*)d_in[5];
    const float* bfc = (const float*)d_in[6];
    float* out = (float*)d_out;

    const int nimg = in_sizes[0] / 784;
    const int imgs_per_block = PAIRS_PER_BLOCK * 2;
    const int grid = (nimg + imgs_per_block - 1) / imgs_per_block;

    fused_cnn_kernel<<<grid, 256, 0, stream>>>(x, W1, b1, W2, b2, Wfc, bfc,
                                               out, nimg);
}

// Round 3
// 418.235 us; speedup vs baseline: 1.2417x; 1.0075x over previous
//
#include <hip/hip_runtime.h>
#include <math.h>

// Fused CNN classifier: conv(1->8,3x3,s2,p1)+ReLU -> conv(8->16,3x3,s2,p1)+ReLU
//                       -> FC(784->1) -> softplus+0.001 -> 1-exp(-r) -> clip
// B=65536 images of 1x28x28 fp32.
//
// R3: same packed-fp32 structure as R2, but the 7x7 window is PINNED into
// VGPRs via a volatile empty inline-asm "+v" on each loaded value. R1/R2
// post-mortems: VGPR_Count 44/84 proved LLVM sank the window ds_reads into
// every use site (legal even across __syncthreads since P is never written
// after), making the kernel LDS-data-path bound (~650 ds_read_b64/wave).
// An asm-defined value cannot be rematerialized as a load, so win[] must
// live in registers (~150-190 VGPRs, fits under launch_bounds(256,2)).
// Expected floor: ~2100 VALU instr x 2cyc x 32 wave-pairs/SIMD ~= 57us.

typedef float v2f __attribute__((ext_vector_type(2)));

__device__ __forceinline__ v2f pk_fma(v2f a, float s, v2f c) {
    v2f b = {s, s};
    return __builtin_elementwise_fma(a, b, c);
}
__device__ __forceinline__ v2f pk_relu(v2f a) {
    v2f z = {0.f, 0.f};
    return __builtin_elementwise_max(a, z);
}

#define PAIRS_PER_BLOCK 4          // 4 waves, 1 image-pair per wave
#define P_ROWS 30
#define P_STRIDE 31
#define P_ELEMS (P_ROWS * P_STRIDE)   // 930 v2f per pair

__global__ __launch_bounds__(256, 2) void fused_cnn_kernel(
    const float* __restrict__ x,
    const float* __restrict__ W1, const float* __restrict__ b1,
    const float* __restrict__ W2, const float* __restrict__ b2,
    const float* __restrict__ Wfc, const float* __restrict__ bfc,
    float* __restrict__ out, int nimg)
{
    __shared__ v2f P[PAIRS_PER_BLOCK * P_ELEMS];   // ~29.8 KB

    const int tid  = threadIdx.x;
    const int img0 = blockIdx.x * (PAIRS_PER_BLOCK * 2);

    // Zero LDS (covers the zero-padding border).
    for (int i = tid; i < PAIRS_PER_BLOCK * P_ELEMS; i += 256)
        P[i] = (v2f){0.f, 0.f};
    __syncthreads();

    // Stage 8 images as 4 interleaved pairs. 4 pairs x 196 float4-positions.
    for (int f = tid; f < PAIRS_PER_BLOCK * 196; f += 256) {
        const int pair = f / 196;
        const int pos4 = f - pair * 196;
        const int imgA = img0 + pair * 2;
        float4 a = {0.f, 0.f, 0.f, 0.f}, b = {0.f, 0.f, 0.f, 0.f};
        if (imgA < nimg)
            a = *(const float4*)(x + (size_t)imgA * 784 + pos4 * 4);
        if (imgA + 1 < nimg)
            b = *(const float4*)(x + (size_t)(imgA + 1) * 784 + pos4 * 4);
        const int flat = pos4 * 4;
        const int yy   = flat / 28;
        const int xx   = flat - yy * 28;
        v2f* dst = &P[pair * P_ELEMS + (yy + 1) * P_STRIDE + (xx + 1)];
        dst[0] = (v2f){a.x, b.x};
        dst[1] = (v2f){a.y, b.y};
        dst[2] = (v2f){a.z, b.z};
        dst[3] = (v2f){a.w, b.w};
    }
    __syncthreads();

    const int wave = tid >> 6;
    const int lane = tid & 63;
    const int imgA = img0 + wave * 2;
    const v2f* __restrict__ Pp = &P[wave * P_ELEMS];

    // All 64 lanes run the compute (lanes 49..63 clamp to lane 48's window and
    // are masked out at the FC fold) so control flow stays wave-uniform.
    const int laneC = lane < 49 ? lane : 48;
    const int oy = laneC / 7;          // conv2 output row 0..6
    const int ox = laneC - oy * 7;     // conv2 output col 0..6

    // 7x7 input window (padded coords), rows/cols 4o-2..4o+4. Negative coords
    // clamp to 0: garbage there only feeds z1 positions masked to zero below.
    // Each value is pinned into a VGPR by a volatile asm: the compiler cannot
    // rematerialize it as an LDS read afterwards.
    v2f win[7][7];
    {
        const int rbase = 4 * oy - 2;
        const int cbase = 4 * ox - 2;
        #pragma unroll
        for (int r = 0; r < 7; r++) {
            int rr = rbase + r; rr = rr < 0 ? 0 : rr;
            const v2f* rowp = Pp + rr * P_STRIDE;
            #pragma unroll
            for (int c = 0; c < 7; c++) {
                int cc = cbase + c; cc = cc < 0 ? 0 : cc;
                v2f t = rowp[cc];
                asm volatile("" : "+v"(t));   // pin: value now lives in VGPRs
                win[r][c] = t;
            }
        }
    }

    v2f acc[16];
    #pragma unroll
    for (int i = 0; i < 16; i++) acc[i] = (v2f){0.f, 0.f};

    for (int c1 = 0; c1 < 8; c1++) {       // uniform -> weights in SGPRs
        const float bb = b1[c1];
        float w1r[9];
        #pragma unroll
        for (int k = 0; k < 9; k++) w1r[k] = W1[c1 * 9 + k];

        // z1 element at window pos (wy,wx); input rel index (2wy+ky, 2wx+kx).
        // Mask positions outside the 14x14 z1 map (conv2 zero-padding), then
        // immediately fold into all 16 conv2 accumulators (no z1 array).
        #pragma unroll
        for (int wy = 0; wy < 3; wy++) {
            #pragma unroll
            for (int wx = 0; wx < 3; wx++) {
                v2f v = {bb, bb};
                #pragma unroll
                for (int ky = 0; ky < 3; ky++)
                    #pragma unroll
                    for (int kx = 0; kx < 3; kx++)
                        v = pk_fma(win[2 * wy + ky][2 * wx + kx],
                                   w1r[ky * 3 + kx], v);
                const bool okm = ((wy > 0) || (oy > 0)) &&
                                 ((wx > 0) || (ox > 0));
                const float m = okm ? 1.f : 0.f;
                v = pk_relu(v);
                v2f mm = {m, m};
                v = v * mm;

                const float* __restrict__ w2k = W2 + c1 * 9 + wy * 3 + wx;
                #pragma unroll
                for (int c2 = 0; c2 < 16; c2++)
                    acc[c2] = pk_fma(v, w2k[c2 * 72], acc[c2]);
            }
        }
    }

    // bias + ReLU + FC fold. Flatten index = c2*49 + lane; lanes>=49 get 0.
    v2f fc = {0.f, 0.f};
    #pragma unroll
    for (int c2 = 0; c2 < 16; c2++) {
        v2f z = pk_relu(pk_fma((v2f){1.f, 1.f}, b2[c2], acc[c2]));
        const float wf = (lane < 49) ? Wfc[c2 * 49 + laneC] : 0.f;
        v2f wfv = {wf, wf};
        fc = __builtin_elementwise_fma(z, wfv, fc);
    }

    // Wave-wide sum of both components.
    float fx = fc.x, fy = fc.y;
    #pragma unroll
    for (int off = 32; off > 0; off >>= 1) {
        fx += __shfl_down(fx, off, 64);
        fy += __shfl_down(fy, off, 64);
    }

    if (lane == 0) {
        const float bias = bfc[0];
        #pragma unroll
        for (int s = 0; s < 2; s++) {
            const int img = imgA + s;
            if (img < nimg) {
                float v    = (s == 0 ? fx : fy) + bias;
                float sp   = fmaxf(v, 0.f) + log1pf(expf(-fabsf(v)));
                float rate = sp + 0.001f;
                float p    = 1.f - expf(-rate);
                p = fminf(fmaxf(p, 1e-6f), 1.f - 1e-6f);
                out[img] = p;
            }
        }
    }
}

extern "C" void kernel_launch(void* const* d_in, const int* in_sizes, int n_in,
                              void* d_out, int out_size, void* d_ws, size_t ws_size,
                              hipStream_t stream) {
    const float* x   = (const float*)d_in[0];
    const float* W1  = (const float*)d_in[1];
    const float* b1  = (const float*)d_in[2];
    const float* W2  = (const float*)d_in[3];
    const float* b2  = (const float*)d_in[4];
    const float* Wfc = (const float*)d_in[5];
    const float* bfc = (const float*)d_in[6];
    float* out = (float*)d_out;

    const int nimg = in_sizes[0] / 784;
    const int imgs_per_block = PAIRS_PER_BLOCK * 2;
    const int grid = (nimg + imgs_per_block - 1) / imgs_per_block;

    fused_cnn_kernel<<<grid, 256, 0, stream>>>(x, W1, b1, W2, b2, Wfc, bfc,
                                               out, nimg);
}